// Round 2
// baseline (457.224 us; speedup 1.0000x reference)
//
#include <hip/hip_runtime.h>

// Per-row MLP 5->120->84->5 + L2-normalize + mask.
// One thread per row. NO LDS: all weight/bias reads use wave-uniform
// addresses (loop indices only) so the compiler promotes them to SGPR
// s_load + v_fma with SGPR operand. h1[120] lives in VGPRs (all indexing
// compile-time constant via full unroll). Layers 2+3 fused; g blocked x4
// for 4 independent accumulate chains.

__global__ __launch_bounds__(256, 3) void nn_rows_sgpr_kernel(
    const float* __restrict__ x,
    const float* __restrict__ W1, const float* __restrict__ b1,
    const float* __restrict__ W2, const float* __restrict__ b2,
    const float* __restrict__ W3, const float* __restrict__ b3,
    float* __restrict__ out, int nrows)
{
    const int row = blockIdx.x * 256 + threadIdx.x;
    if (row >= nrows) return;

    const float* xr = x + (size_t)row * 5;
    float xv[5];
#pragma unroll
    for (int i = 0; i < 5; ++i) xv[i] = xr[i];

    // ---- layer 1: h1 = relu(W1 @ x + b1), kept entirely in VGPRs ----
    float h1[120];
#pragma unroll
    for (int h = 0; h < 120; ++h) {
        float a = b1[h];                       // uniform -> SGPR
        a = fmaf(W1[h * 5 + 0], xv[0], a);
        a = fmaf(W1[h * 5 + 1], xv[1], a);
        a = fmaf(W1[h * 5 + 2], xv[2], a);
        a = fmaf(W1[h * 5 + 3], xv[3], a);
        a = fmaf(W1[h * 5 + 4], xv[4], a);
        h1[h] = fmaxf(a, 0.0f);
    }

    // ---- layers 2+3 fused: y[o] += W3[o][g] * relu(W2[g]·h1 + b2[g]) ----
    float y[5];
#pragma unroll
    for (int o = 0; o < 5; ++o) y[o] = b3[o];

    for (int g = 0; g < 84; g += 4) {          // rolled: g stays uniform
        const float* p0 = W2 + (size_t)(g + 0) * 120;
        const float* p1 = W2 + (size_t)(g + 1) * 120;
        const float* p2 = W2 + (size_t)(g + 2) * 120;
        const float* p3 = W2 + (size_t)(g + 3) * 120;
        float a0 = b2[g + 0];
        float a1 = b2[g + 1];
        float a2 = b2[g + 2];
        float a3 = b2[g + 3];
#pragma unroll
        for (int h = 0; h < 120; ++h) {        // full unroll: h1[] static idx
            const float hv = h1[h];
            a0 = fmaf(p0[h], hv, a0);
            a1 = fmaf(p1[h], hv, a1);
            a2 = fmaf(p2[h], hv, a2);
            a3 = fmaf(p3[h], hv, a3);
        }
        a0 = fmaxf(a0, 0.0f);
        a1 = fmaxf(a1, 0.0f);
        a2 = fmaxf(a2, 0.0f);
        a3 = fmaxf(a3, 0.0f);
#pragma unroll
        for (int o = 0; o < 5; ++o) {
            const float* w3o = W3 + o * 84 + g;
            float t = y[o];
            t = fmaf(w3o[0], a0, t);
            t = fmaf(w3o[1], a1, t);
            t = fmaf(w3o[2], a2, t);
            t = fmaf(w3o[3], a3, t);
            y[o] = t;
        }
    }

    // ---- relu + L2 normalize over the 5 outputs + x!=0 mask ----
#pragma unroll
    for (int o = 0; o < 5; ++o) y[o] = fmaxf(y[o], 0.0f);

    float ss = y[0] * y[0];
    ss = fmaf(y[1], y[1], ss);
    ss = fmaf(y[2], y[2], ss);
    ss = fmaf(y[3], y[3], ss);
    ss = fmaf(y[4], y[4], ss);
    const float denom = fmaxf(sqrtf(ss), 1e-12f);
    const float inv = 1.0f / denom;

    float* outr = out + (size_t)row * 5;
#pragma unroll
    for (int o = 0; o < 5; ++o) {
        outr[o] = (xv[o] != 0.0f) ? 0.0f : (y[o] * inv);
    }
}

extern "C" void kernel_launch(void* const* d_in, const int* in_sizes, int n_in,
                              void* d_out, int out_size, void* d_ws, size_t ws_size,
                              hipStream_t stream) {
    const float* x  = (const float*)d_in[0];
    const float* W1 = (const float*)d_in[1];
    const float* b1 = (const float*)d_in[2];
    const float* W2 = (const float*)d_in[3];
    const float* b2 = (const float*)d_in[4];
    const float* W3 = (const float*)d_in[5];
    const float* b3 = (const float*)d_in[6];
    float* out = (float*)d_out;

    const int nrows = in_sizes[0] / 5;
    const int block = 256;
    const int grid = (nrows + block - 1) / block;
    nn_rows_sgpr_kernel<<<grid, block, 0, stream>>>(x, W1, b1, W2, b2, W3, b3, out, nrows);
}

// Round 3
// 347.399 us; speedup vs baseline: 1.3161x; 1.3161x over previous
//
#include <hip/hip_runtime.h>

// Per-row MLP 5->120->84->5 + relu + L2-normalize + x!=0 mask.
// Kernel 1: transpose W2 [84][120] -> W2T [120][84] in d_ws (40 KB).
// Kernel 2: one thread per row. Weights read via wave-uniform addresses ->
// scalar s_load (SMEM pipe), zero LDS. Layer 2 is g-split into two passes of
// 42 so the live set is acc[42] (VGPR) + 42 weight floats (SGPR) -- no h1[120]
// array, no spill, no rematerialization blowup. Layer 1 recomputed per pass
// (+600 FMA/row, +5%).

__global__ __launch_bounds__(256) void transpose_w2_kernel(
    const float* __restrict__ W2, float* __restrict__ W2T)
{
    int i = blockIdx.x * 256 + threadIdx.x;   // over 84*120
    if (i < 84 * 120) {
        int g = i / 120;
        int h = i - g * 120;
        W2T[h * 84 + g] = W2[i];
    }
}

template <int G0>
__device__ __forceinline__ void half_pass(
    const float xv[5],
    const float* __restrict__ W1, const float* __restrict__ b1,
    const float* __restrict__ W2T, const float* __restrict__ b2,
    const float* __restrict__ W3,
    float y[5])
{
    float acc[42];
#pragma unroll
    for (int g = 0; g < 42; ++g) acc[g] = b2[G0 + g];

    for (int h = 0; h < 120; ++h) {            // rolled; h stays uniform
        float a = b1[h];
        a = fmaf(W1[h * 5 + 0], xv[0], a);
        a = fmaf(W1[h * 5 + 1], xv[1], a);
        a = fmaf(W1[h * 5 + 2], xv[2], a);
        a = fmaf(W1[h * 5 + 3], xv[3], a);
        a = fmaf(W1[h * 5 + 4], xv[4], a);
        a = fmaxf(a, 0.0f);                    // h1[h]
        const float* w = W2T + h * 84 + G0;    // uniform, contiguous 42 floats
#pragma unroll
        for (int g = 0; g < 42; ++g) acc[g] = fmaf(w[g], a, acc[g]);
    }

#pragma unroll
    for (int g = 0; g < 42; ++g) acc[g] = fmaxf(acc[g], 0.0f);   // relu(h2)

#pragma unroll
    for (int o = 0; o < 5; ++o) {
        const float* w3o = W3 + o * 84 + G0;   // uniform
        float t = y[o];
#pragma unroll
        for (int g = 0; g < 42; ++g) t = fmaf(w3o[g], acc[g], t);
        y[o] = t;
    }
}

__global__ __launch_bounds__(256, 4) void nn_rows_gsplit_kernel(
    const float* __restrict__ x,
    const float* __restrict__ W1, const float* __restrict__ b1,
    const float* __restrict__ W2T, const float* __restrict__ b2,
    const float* __restrict__ W3, const float* __restrict__ b3,
    float* __restrict__ out, int nrows)
{
    const int row = blockIdx.x * 256 + threadIdx.x;
    if (row >= nrows) return;

    const float* xr = x + (size_t)row * 5;
    float xv[5];
#pragma unroll
    for (int i = 0; i < 5; ++i) xv[i] = xr[i];

    float y[5];
#pragma unroll
    for (int o = 0; o < 5; ++o) y[o] = b3[o];

    half_pass<0>(xv, W1, b1, W2T, b2, W3, y);
    half_pass<42>(xv, W1, b1, W2T, b2, W3, y);

#pragma unroll
    for (int o = 0; o < 5; ++o) y[o] = fmaxf(y[o], 0.0f);

    float ss = y[0] * y[0];
    ss = fmaf(y[1], y[1], ss);
    ss = fmaf(y[2], y[2], ss);
    ss = fmaf(y[3], y[3], ss);
    ss = fmaf(y[4], y[4], ss);
    const float denom = fmaxf(sqrtf(ss), 1e-12f);
    const float inv = 1.0f / denom;

    float* outr = out + (size_t)row * 5;
#pragma unroll
    for (int o = 0; o < 5; ++o) {
        outr[o] = (xv[o] != 0.0f) ? 0.0f : (y[o] * inv);
    }
}

extern "C" void kernel_launch(void* const* d_in, const int* in_sizes, int n_in,
                              void* d_out, int out_size, void* d_ws, size_t ws_size,
                              hipStream_t stream) {
    const float* x  = (const float*)d_in[0];
    const float* W1 = (const float*)d_in[1];
    const float* b1 = (const float*)d_in[2];
    const float* W2 = (const float*)d_in[3];
    const float* b2 = (const float*)d_in[4];
    const float* W3 = (const float*)d_in[5];
    const float* b3 = (const float*)d_in[6];
    float* out = (float*)d_out;
    float* W2T = (float*)d_ws;                 // 120*84*4 = 40320 B

    transpose_w2_kernel<<<(84 * 120 + 255) / 256, 256, 0, stream>>>(W2, W2T);

    const int nrows = in_sizes[0] / 5;
    const int block = 256;
    const int grid = (nrows + block - 1) / block;
    nn_rows_gsplit_kernel<<<grid, block, 0, stream>>>(x, W1, b1, W2T, b2, W3, b3, out, nrows);
}

// Round 5
// 321.842 us; speedup vs baseline: 1.4207x; 1.0794x over previous
//
#include <hip/hip_runtime.h>

// Per-row MLP 5->120->84->5 + relu + L2-normalize + x!=0 mask.
// R5: packed FP32 (VOP3P v_pk_fma_f32) for layer-2/3 inner loops. gfx950 has
// v_pk_fma_f32 but NOT v_pk_max_f32 (R4 compile error) -> relu done with
// component-wise scalar fmaxf. Weights wave-uniform -> SGPR pairs ("s" asm
// operand); accumulators/activations in VGPR pairs. Structure = R3 (g-split
// x2 passes, zero LDS, W2 transposed into d_ws by a prelude kernel).

typedef float v2f __attribute__((ext_vector_type(2)));

// acc[2xf32] += w[2xf32](SGPR pair) * a2[2xf32](VGPR pair)
#define PK_FMA_S(acc, w, a2) \
    asm("v_pk_fma_f32 %0, %1, %2, %0" : "+v"(acc) : "s"(w), "v"(a2))

__global__ __launch_bounds__(256) void transpose_w2_kernel(
    const float* __restrict__ W2, float* __restrict__ W2T)
{
    int i = blockIdx.x * 256 + threadIdx.x;   // over 84*120
    if (i < 84 * 120) {
        int g = i / 120;
        int h = i - g * 120;
        W2T[h * 84 + g] = W2[i];
    }
}

template <int G0>
__device__ __forceinline__ void half_pass(
    const float xv[5],
    const float* __restrict__ W1, const float* __restrict__ b1,
    const float* __restrict__ W2T, const float* __restrict__ b2,
    const float* __restrict__ W3,
    v2f ysum[5])
{
    v2f acc[21];
#pragma unroll
    for (int gp = 0; gp < 21; ++gp)
        acc[gp] = *(const v2f*)(b2 + G0 + 2 * gp);   // uniform -> s_load

    for (int h = 0; h < 120; ++h) {            // rolled; h stays uniform
        float a = b1[h];
        a = fmaf(W1[h * 5 + 0], xv[0], a);
        a = fmaf(W1[h * 5 + 1], xv[1], a);
        a = fmaf(W1[h * 5 + 2], xv[2], a);
        a = fmaf(W1[h * 5 + 3], xv[3], a);
        a = fmaf(W1[h * 5 + 4], xv[4], a);
        a = fmaxf(a, 0.0f);                    // h1[h]
        v2f a2;
        a2[0] = a; a2[1] = a;
        const float* w = W2T + h * 84 + G0;    // uniform, contiguous
#pragma unroll
        for (int gp = 0; gp < 21; ++gp) {
            const double wp = *(const double*)(w + 2 * gp);  // SGPR pair
            PK_FMA_S(acc[gp], wp, a2);
        }
    }

#pragma unroll
    for (int gp = 0; gp < 21; ++gp) {          // relu(h2), scalar (no pk_max)
        acc[gp][0] = fmaxf(acc[gp][0], 0.0f);
        acc[gp][1] = fmaxf(acc[gp][1], 0.0f);
    }

#pragma unroll
    for (int o = 0; o < 5; ++o) {
        const float* w3o = W3 + o * 84 + G0;   // uniform
#pragma unroll
        for (int gp = 0; gp < 21; ++gp) {
            const double wp = *(const double*)(w3o + 2 * gp);
            PK_FMA_S(ysum[o], wp, acc[gp]);
        }
    }
}

__global__ __launch_bounds__(256, 4) void nn_rows_pk_kernel(
    const float* __restrict__ x,
    const float* __restrict__ W1, const float* __restrict__ b1,
    const float* __restrict__ W2T, const float* __restrict__ b2,
    const float* __restrict__ W3, const float* __restrict__ b3,
    float* __restrict__ out, int nrows)
{
    const int row = blockIdx.x * 256 + threadIdx.x;
    if (row >= nrows) return;

    const float* xr = x + (size_t)row * 5;
    float xv[5];
#pragma unroll
    for (int i = 0; i < 5; ++i) xv[i] = xr[i];

    v2f ysum[5];
#pragma unroll
    for (int o = 0; o < 5; ++o) { ysum[o][0] = 0.0f; ysum[o][1] = 0.0f; }

    half_pass<0>(xv, W1, b1, W2T, b2, W3, ysum);
    half_pass<42>(xv, W1, b1, W2T, b2, W3, ysum);

    float y[5];
#pragma unroll
    for (int o = 0; o < 5; ++o)
        y[o] = fmaxf(b3[o] + ysum[o][0] + ysum[o][1], 0.0f);

    float ss = y[0] * y[0];
    ss = fmaf(y[1], y[1], ss);
    ss = fmaf(y[2], y[2], ss);
    ss = fmaf(y[3], y[3], ss);
    ss = fmaf(y[4], y[4], ss);
    const float denom = fmaxf(sqrtf(ss), 1e-12f);
    const float inv = 1.0f / denom;

    float* outr = out + (size_t)row * 5;
#pragma unroll
    for (int o = 0; o < 5; ++o) {
        outr[o] = (xv[o] != 0.0f) ? 0.0f : (y[o] * inv);
    }
}

extern "C" void kernel_launch(void* const* d_in, const int* in_sizes, int n_in,
                              void* d_out, int out_size, void* d_ws, size_t ws_size,
                              hipStream_t stream) {
    const float* x  = (const float*)d_in[0];
    const float* W1 = (const float*)d_in[1];
    const float* b1 = (const float*)d_in[2];
    const float* W2 = (const float*)d_in[3];
    const float* b2 = (const float*)d_in[4];
    const float* W3 = (const float*)d_in[5];
    const float* b3 = (const float*)d_in[6];
    float* out = (float*)d_out;
    float* W2T = (float*)d_ws;                 // 120*84*4 = 40320 B

    transpose_w2_kernel<<<(84 * 120 + 255) / 256, 256, 0, stream>>>(W2, W2T);

    const int nrows = in_sizes[0] / 5;
    const int block = 256;
    const int grid = (nrows + block - 1) / block;
    nn_rows_pk_kernel<<<grid, block, 0, stream>>>(x, W1, b1, W2T, b2, W3, b3, out, nrows);
}

// Round 7
// 244.310 us; speedup vs baseline: 1.8715x; 1.3173x over previous
//
#include <hip/hip_runtime.h>

// Per-row MLP 5->120->84->5 + relu + L2-normalize + x!=0 mask.
// R7 = R6 with the LDS staging index bug fixed: sW2/sW3 rows are 256 B =
// 16 float4 chunks, so chunk c decomposes as r=c>>4, s=c&15 (R6 used
// c>>3/c&7 -> OOB LDS writes corrupting sW3 -> Inf*0=NaN). Also force
// 16-byte alignment on LDS arrays.
//  - pack_kernel: f16-cast + zero-pad weights into d_ws; W2T f32 for rescue.
//  - mfma_main: wave = 16 rows; W2/W3 + h1/h2 in XOR-swizzled LDS;
//    3 layers on mfma_f32_16x16x32_f16 (f32 accum); rows with ||y||^2 < TAU2
//    appended to a rescue list (atomicAdd compaction).
//  - rescue_kernel: exact f32 recompute (R3 structure) for listed rows.

typedef _Float16 f16x8 __attribute__((ext_vector_type(8)));
typedef float    f32x4 __attribute__((ext_vector_type(4)));

#define CNT_OFF  0
#define W2T_OFF  64
#define W1P_OFF  40384
#define W2P_OFF  48576
#define W3P_OFF  73152
#define LIST_OFF 77312
#define TAU2     0.0625f   // rescue if ||y||^2 < 0.25^2

// ---------------- pack ----------------
__global__ __launch_bounds__(256) void pack_kernel(
    const float* __restrict__ W1, const float* __restrict__ W2,
    const float* __restrict__ W3, char* __restrict__ ws)
{
    int i = blockIdx.x * 256 + threadIdx.x;
    if (i == 0) *(unsigned int*)(ws + CNT_OFF) = 0u;
    _Float16* W1p = (_Float16*)(ws + W1P_OFF);   // [128][32]
    _Float16* W2p = (_Float16*)(ws + W2P_OFF);   // [96][128]
    _Float16* W3p = (_Float16*)(ws + W3P_OFF);   // [16][128]
    float*    W2T = (float*)(ws + W2T_OFF);      // [120][84]
    if (i < 4096)  { int r = i >> 5, k = i & 31;
        W1p[i] = (_Float16)((r < 120 && k < 5)   ? W1[r*5 + k]    : 0.f); }
    if (i < 12288) { int r = i >> 7, k = i & 127;
        W2p[i] = (_Float16)((r < 84  && k < 120) ? W2[r*120 + k]  : 0.f); }
    if (i < 2048)  { int r = i >> 7, k = i & 127;
        W3p[i] = (_Float16)((r < 5   && k < 84)  ? W3[r*84 + k]   : 0.f); }
    if (i < 10080) { int g = i / 120, h = i - g*120; W2T[h*84 + g] = W2[i]; }
}

// ---------------- main (MFMA) ----------------
__global__ __launch_bounds__(256, 2) void mfma_main(
    const float* __restrict__ x, const float* __restrict__ b1,
    const float* __restrict__ b2, const float* __restrict__ b3,
    const char* __restrict__ ws, float* __restrict__ out,
    unsigned int* __restrict__ cnt, unsigned int* __restrict__ list,
    unsigned int cap, int nrows)
{
    __shared__ __align__(16) _Float16 sW2[96 * 128];     // 24.0 KB, swizzled
    __shared__ __align__(16) _Float16 sW3[16 * 128];     //  4.0 KB, swizzled
    __shared__ __align__(16) _Float16 sh1[4][16 * 128];  // 16.0 KB, swizzled
    __shared__ __align__(16) _Float16 sh2[4][16 * 128];  // 16.0 KB, swizzled
    __shared__ __align__(16) float    sy [4][16 * 8];    //  2.0 KB

    const _Float16* W1p = (const _Float16*)(ws + W1P_OFF);
    const _Float16* W2p = (const _Float16*)(ws + W2P_OFF);
    const _Float16* W3p = (const _Float16*)(ws + W3P_OFF);

    const int tid = threadIdx.x;
    // stage W2p -> sW2: 96 rows x 256B = 1536 16B chunks (16 chunks/row).
    for (int c = tid; c < 1536; c += 256) {
        int r = c >> 4, s = c & 15;
        float4 v = *(const float4*)(W2p + c * 8);
        *(float4*)((char*)sW2 + r*256 + ((s*16) ^ ((r & 7) << 4))) = v;
    }
    {   // stage W3p -> sW3: 16 rows x 16 chunks = 256 chunks, one per thread
        int c = tid, r = c >> 4, s = c & 15;
        float4 v = *(const float4*)(W3p + c * 8);
        *(float4*)((char*)sW3 + r*256 + ((s*16) ^ ((r & 7) << 4))) = v;
    }
    __syncthreads();

    const int w = tid >> 6, lane = tid & 63;
    const int col = lane & 15, q = lane >> 4;
    const long rowbase = (long)blockIdx.x * 64 + w * 16;
    char* sh1w = (char*)sh1[w];
    char* sh2w = (char*)sh2[w];

    // per-lane biases (masked at padding)
    float b1v[8], b2v[6], b3v;
#pragma unroll
    for (int n = 0; n < 8; ++n) { int f = n*16 + col; b1v[n] = (f < 120) ? b1[f] : 0.f; }
#pragma unroll
    for (int n = 0; n < 6; ++n) { int f = n*16 + col; b2v[n] = (f < 84)  ? b2[f] : 0.f; }
    b3v = (col < 5) ? b3[col] : 0.f;

    // x A-frag: row = lane&15, k = q*8+j (k>=5 zero)
    f16x8 ax;
#pragma unroll
    for (int j = 0; j < 8; ++j) ax[j] = (_Float16)0.f;
    {
        const long grow0 = rowbase + col;
        if (q == 0 && grow0 < nrows) {
            const float* xp = x + grow0 * 5;
            ax[0] = (_Float16)xp[0]; ax[1] = (_Float16)xp[1];
            ax[2] = (_Float16)xp[2]; ax[3] = (_Float16)xp[3];
            ax[4] = (_Float16)xp[4];
        }
    }

    // ---- L1: h1[16x120] = relu(x @ W1^T + b1), written f16 to sh1 ----
#pragma unroll
    for (int n = 0; n < 8; ++n) {
        f16x8 bf = *(const f16x8*)(W1p + ((n*16 + col) * 32 + q * 8));
        f32x4 c = __builtin_amdgcn_mfma_f32_16x16x32_f16(
            ax, bf, (f32x4){0.f, 0.f, 0.f, 0.f}, 0, 0, 0);
#pragma unroll
        for (int j = 0; j < 4; ++j) {
            float v = fmaxf(c[j] + b1v[n], 0.f);
            int r = q*4 + j;
            *(_Float16*)(sh1w + r*256 + ((((n*16 + col)) * 2) ^ ((r & 7) << 4))) =
                (_Float16)v;
        }
    }

    // ---- L2: h2[16x84] = relu(h1 @ W2^T + b2) ----
    f32x4 acc[6];
#pragma unroll
    for (int n = 0; n < 6; ++n) acc[n] = (f32x4){0.f, 0.f, 0.f, 0.f};
#pragma unroll
    for (int t = 0; t < 4; ++t) {
        f16x8 af = *(const f16x8*)(sh1w + col*256 +
                                   ((t*64 + q*16) ^ ((col & 7) << 4)));
#pragma unroll
        for (int n = 0; n < 6; ++n) {
            int br = n*16 + col;
            f16x8 bf = *(const f16x8*)((const char*)sW2 + br*256 +
                                       ((t*64 + q*16) ^ ((br & 7) << 4)));
            acc[n] = __builtin_amdgcn_mfma_f32_16x16x32_f16(af, bf, acc[n], 0, 0, 0);
        }
    }
#pragma unroll
    for (int n = 0; n < 6; ++n) {
#pragma unroll
        for (int j = 0; j < 4; ++j) {
            float v = fmaxf(acc[n][j] + b2v[n], 0.f);
            int r = q*4 + j;
            *(_Float16*)(sh2w + r*256 + ((((n*16 + col)) * 2) ^ ((r & 7) << 4))) =
                (_Float16)v;
        }
    }

    // ---- L3: y[16x5] = relu(h2 @ W3^T + b3) ----
    f32x4 acy = (f32x4){0.f, 0.f, 0.f, 0.f};
#pragma unroll
    for (int t = 0; t < 3; ++t) {
        f16x8 af = *(const f16x8*)(sh2w + col*256 +
                                   ((t*64 + q*16) ^ ((col & 7) << 4)));
        f16x8 bf = *(const f16x8*)((const char*)sW3 + col*256 +
                                   ((t*64 + q*16) ^ ((col & 7) << 4)));
        acy = __builtin_amdgcn_mfma_f32_16x16x32_f16(af, bf, acy, 0, 0, 0);
    }
    if (col < 5) {
#pragma unroll
        for (int j = 0; j < 4; ++j)
            sy[w][(q*4 + j) * 8 + col] = fmaxf(acy[j] + b3v, 0.f);
    }

    // ---- epilogue: normalize + mask + rescue flag (lanes 0..15) ----
    if (lane < 16) {
        long grow = rowbase + lane;
        if (grow < nrows) {
            float y0 = sy[w][lane*8 + 0], y1 = sy[w][lane*8 + 1],
                  y2 = sy[w][lane*8 + 2], y3 = sy[w][lane*8 + 3],
                  y4 = sy[w][lane*8 + 4];
            float ss = y0*y0 + y1*y1 + y2*y2 + y3*y3 + y4*y4;
            float inv = 1.0f / fmaxf(sqrtf(ss), 1e-12f);
            const float* xp = x + grow * 5;
            float* op = out + grow * 5;
            op[0] = (xp[0] != 0.f) ? 0.f : y0 * inv;
            op[1] = (xp[1] != 0.f) ? 0.f : y1 * inv;
            op[2] = (xp[2] != 0.f) ? 0.f : y2 * inv;
            op[3] = (xp[3] != 0.f) ? 0.f : y3 * inv;
            op[4] = (xp[4] != 0.f) ? 0.f : y4 * inv;
            if (ss < TAU2) {
                unsigned int idx = atomicAdd(cnt, 1u);
                if (idx < cap) list[idx] = (unsigned int)grow;
            }
        }
    }
}

// ---------------- rescue (exact f32, R3 structure) ----------------
template <int G0>
__device__ __forceinline__ void half_pass(
    const float xv[5],
    const float* __restrict__ W1, const float* __restrict__ b1,
    const float* __restrict__ W2T, const float* __restrict__ b2,
    const float* __restrict__ W3,
    float y[5])
{
    float acc[42];
#pragma unroll
    for (int g = 0; g < 42; ++g) acc[g] = b2[G0 + g];
    for (int h = 0; h < 120; ++h) {
        float a = b1[h];
        a = fmaf(W1[h*5 + 0], xv[0], a);
        a = fmaf(W1[h*5 + 1], xv[1], a);
        a = fmaf(W1[h*5 + 2], xv[2], a);
        a = fmaf(W1[h*5 + 3], xv[3], a);
        a = fmaf(W1[h*5 + 4], xv[4], a);
        a = fmaxf(a, 0.0f);
        const float* wr = W2T + h*84 + G0;
#pragma unroll
        for (int g = 0; g < 42; ++g) acc[g] = fmaf(wr[g], a, acc[g]);
    }
#pragma unroll
    for (int g = 0; g < 42; ++g) acc[g] = fmaxf(acc[g], 0.0f);
#pragma unroll
    for (int o = 0; o < 5; ++o) {
        const float* w3o = W3 + o*84 + G0;
        float t = y[o];
#pragma unroll
        for (int g = 0; g < 42; ++g) t = fmaf(w3o[g], acc[g], t);
        y[o] = t;
    }
}

__global__ __launch_bounds__(256) void rescue_kernel(
    const float* __restrict__ x,
    const float* __restrict__ W1, const float* __restrict__ b1,
    const char*  __restrict__ ws, const float* __restrict__ b2,
    const float* __restrict__ W3, const float* __restrict__ b3,
    float* __restrict__ out, unsigned int cap)
{
    const unsigned int* cnt  = (const unsigned int*)(ws + CNT_OFF);
    const unsigned int* list = (const unsigned int*)(ws + LIST_OFF);
    const float* W2T = (const float*)(ws + W2T_OFF);
    unsigned int count = *cnt;
    if (count > cap) count = cap;
    unsigned int tid = blockIdx.x * 256 + threadIdx.x;
    if (tid >= count) return;
    long row = (long)list[tid];

    const float* xr = x + row * 5;
    float xv[5];
#pragma unroll
    for (int i = 0; i < 5; ++i) xv[i] = xr[i];

    float y[5];
#pragma unroll
    for (int o = 0; o < 5; ++o) y[o] = b3[o];
    half_pass<0>(xv, W1, b1, W2T, b2, W3, y);
    half_pass<42>(xv, W1, b1, W2T, b2, W3, y);
#pragma unroll
    for (int o = 0; o < 5; ++o) y[o] = fmaxf(y[o], 0.0f);

    float ss = y[0]*y[0];
    ss = fmaf(y[1], y[1], ss);
    ss = fmaf(y[2], y[2], ss);
    ss = fmaf(y[3], y[3], ss);
    ss = fmaf(y[4], y[4], ss);
    float inv = 1.0f / fmaxf(sqrtf(ss), 1e-12f);
    float* op = out + row * 5;
#pragma unroll
    for (int o = 0; o < 5; ++o)
        op[o] = (xv[o] != 0.f) ? 0.f : y[o] * inv;
}

// ---------------- launch ----------------
extern "C" void kernel_launch(void* const* d_in, const int* in_sizes, int n_in,
                              void* d_out, int out_size, void* d_ws, size_t ws_size,
                              hipStream_t stream) {
    const float* x  = (const float*)d_in[0];
    const float* W1 = (const float*)d_in[1];
    const float* b1 = (const float*)d_in[2];
    const float* W2 = (const float*)d_in[3];
    const float* b2 = (const float*)d_in[4];
    const float* W3 = (const float*)d_in[5];
    const float* b3 = (const float*)d_in[6];
    float* out = (float*)d_out;
    char* ws = (char*)d_ws;

    const int nrows = in_sizes[0] / 5;
    unsigned int cap = (ws_size > (size_t)LIST_OFF + 4)
                       ? (unsigned int)((ws_size - LIST_OFF) / 4) : 0u;
    unsigned int* cnt  = (unsigned int*)(ws + CNT_OFF);
    unsigned int* list = (unsigned int*)(ws + LIST_OFF);

    pack_kernel<<<48, 256, 0, stream>>>(W1, W2, W3, ws);

    const int mblocks = (nrows + 63) / 64;
    mfma_main<<<mblocks, 256, 0, stream>>>(x, b1, b2, b3, ws, out,
                                           cnt, list, cap, nrows);

    const int rblocks = (nrows + 255) / 256;
    rescue_kernel<<<rblocks, 256, 0, stream>>>(x, W1, b1, ws, b2, W3, b3,
                                               out, cap);
}